// Round 4
// baseline (205.507 us; speedup 1.0000x reference)
//
#include <hip/hip_runtime.h>
#include <hip/hip_bf16.h>
#include <cstdint>

#define BB 64
#define NN_ 500
#define NP 512
#define EE 128
#define NHEAD 8
#define HD 16

typedef float f32x4 __attribute__((ext_vector_type(4)));
typedef unsigned u32x4 __attribute__((ext_vector_type(4)));
typedef short s16x8 __attribute__((ext_vector_type(8)));
typedef short s16x4 __attribute__((ext_vector_type(4)));

__device__ __forceinline__ unsigned short f2bf(float f) {
  unsigned u = __builtin_bit_cast(unsigned, f);
  u += 0x7FFFu + ((u >> 16) & 1u);
  return (unsigned short)(u >> 16);
}

__device__ __forceinline__ float bf2f(unsigned short u) {
  unsigned v = ((unsigned)u) << 16;
  return __builtin_bit_cast(float, v);
}

__device__ __forceinline__ unsigned cvtpk(float a, float b) {
  unsigned r;
  asm("v_cvt_pk_bf16_f32 %0, %1, %2" : "=v"(r) : "v"(a), "v"(b));
  return r;
}

__device__ __forceinline__ float EXP2(float x) {
  float r;
  asm("v_exp_f32 %0, %1" : "=v"(r) : "v"(x));
  return r;
}

__device__ __forceinline__ float RCP(float x) {
  float r;
  asm("v_rcp_f32 %0, %1" : "=v"(r) : "v"(x));
  return r;
}

__device__ __forceinline__ s16x8 pack8(f32x4 a, f32x4 b) {
  u32x4 u = { cvtpk(a[0], a[1]), cvtpk(a[2], a[3]), cvtpk(b[0], b[1]), cvtpk(b[2], b[3]) };
  return __builtin_bit_cast(s16x8, u);
}

__device__ __forceinline__ f32x4 MFMA(s16x8 a, s16x8 b, f32x4 c) {
  return __builtin_amdgcn_mfma_f32_16x16x32_bf16(a, b, c, 0, 0, 0);
}

// ---------------- K0a: ef fp32 -> bf16, padded rows 500..511 = 0 ----------------
__global__ void k_conv_ef(const float* __restrict__ ef, unsigned short* __restrict__ out) {
  int idx = blockIdx.x * 256 + threadIdx.x;   // B*NP*16 = 524288
  int e8 = idx & 15;
  int n  = (idx >> 4) & (NP - 1);
  int b  = idx >> 13;
  s16x8 o = {0,0,0,0,0,0,0,0};
  if (n < NN_) {
    const f32x4* p = reinterpret_cast<const f32x4*>(ef + ((size_t)(b * NN_ + n)) * EE + e8 * 8);
    o = pack8(p[0], p[1]);
  }
  *reinterpret_cast<s16x8*>(out + ((size_t)(b * NP + n)) * EE + e8 * 8) = o;
}

// ---------------- K0b: W^T bf16; mats order [q1,q0,k,v,c], WT[m][n][k]=W[k][n] ----------------
__global__ void k_conv_w(const float* __restrict__ w0, const float* __restrict__ w1,
                         const float* __restrict__ w2, const float* __restrict__ w3,
                         const float* __restrict__ w4, unsigned short* __restrict__ wt) {
  int idx = blockIdx.x * 256 + threadIdx.x;   // 5*128*128 = 81920
  int k = idx & 127;
  int n = (idx >> 7) & 127;
  int m = idx >> 14;
  const float* w = (m == 0) ? w0 : (m == 1) ? w1 : (m == 2) ? w2 : (m == 3) ? w3 : w4;
  wt[idx] = f2bf(w[k * 128 + n]);
}

// ---------------- K1: projections -> QH, KH head-major [b][h][n][16], VT [b][h][16][n] ----------------
__global__ __launch_bounds__(256) void k_proj(
    const unsigned short* __restrict__ ef_bf,
    const float* __restrict__ eq1, const float* __restrict__ eq0,
    const unsigned short* __restrict__ wt,
    unsigned short* __restrict__ qh, unsigned short* __restrict__ kh,
    unsigned short* __restrict__ vt_bf) {
  int wgid = blockIdx.x;                 // 1024
  int xcd = wgid & 7;
  int s = wgid >> 3;
  int nt = s & 15;
  int b = (s >> 4) * 8 + xcd;
  int tid = threadIdx.x;
  int w = tid >> 6, lane = tid & 63, g = lane >> 4, c = lane & 15;
  int rw = w & 1, cw = w >> 1;
  int nbase = nt * 32 + rw * 16;

  f32x4 ak[4], av[4], aq[4];
#pragma unroll
  for (int t = 0; t < 4; ++t) { ak[t]=(f32x4){0,0,0,0}; av[t]=(f32x4){0,0,0,0}; aq[t]=(f32x4){0,0,0,0}; }

  int nA = nbase + c;
  int nc = nA < NN_ ? nA : NN_ - 1;

  for (int kk = 0; kk < 4; ++kk) {
    int k0 = kk * 32 + 8 * g;
    s16x8 aef = *reinterpret_cast<const s16x8*>(ef_bf + ((size_t)(b * NP + nA)) * EE + k0);
    const f32x4* p1 = reinterpret_cast<const f32x4*>(eq1 + ((size_t)(b * NN_ + nc)) * EE + k0);
    const f32x4* p0 = reinterpret_cast<const f32x4*>(eq0 + ((size_t)(b * NN_ + nc)) * EE + k0);
    s16x8 a1 = pack8(p1[0], p1[1]);
    s16x8 a0 = pack8(p0[0], p0[1]);
#pragma unroll
    for (int tc = 0; tc < 4; ++tc) {
      int e = cw * 64 + tc * 16 + c;
      const unsigned short* wrow = wt + e * EE + k0;
      s16x8 bq1 = *reinterpret_cast<const s16x8*>(wrow);
      s16x8 bq0 = *reinterpret_cast<const s16x8*>(wrow + 1 * 16384);
      s16x8 bk  = *reinterpret_cast<const s16x8*>(wrow + 2 * 16384);
      s16x8 bv  = *reinterpret_cast<const s16x8*>(wrow + 3 * 16384);
      ak[tc] = MFMA(aef, bk, ak[tc]);
      av[tc] = MFMA(aef, bv, av[tc]);
      aq[tc] = MFMA(a1, bq1, aq[tc]);
      aq[tc] = MFMA(a0, bq0, aq[tc]);
    }
  }
#pragma unroll
  for (int tc = 0; tc < 4; ++tc) {
    int h = cw * 4 + tc;                 // e = cw*64+tc*16+c -> head, d = c
#pragma unroll
    for (int r = 0; r < 4; ++r) {
      int n = nbase + 4 * g + r;
      size_t off = ((size_t)((b * NHEAD + h) * NP) + n) * HD + c;
      kh[off] = f2bf(ak[tc][r]);         // padded rows: ef=0 -> ak=0, naturally safe
      qh[off] = f2bf(aq[tc][r]);         // padded rows garbage-but-finite; outputs unused
    }
    int n0 = nbase + 4 * g;
    unsigned pv0 = cvtpk(av[tc][0], av[tc][1]);
    unsigned pv1 = cvtpk(av[tc][2], av[tc][3]);
    u32x4 dummy;
    *reinterpret_cast<uint2*>(vt_bf + (((size_t)(b * NHEAD + h)) * HD + c) * NP + n0) =
        make_uint2(pv0, pv1);
    (void)dummy;
  }
}

// ---------------- K2: FUSED attn(8 heads) + combine + pointer-logits per (b, 32-row tile) ----------------
// 512 threads = 8 waves: mw = w&3 (m-split 4-way), nw = w>>2 (n-split 2-way).
// No max-subtraction (scores bounded: attn ~ +-4, pointer = 10*tanh in [-10,10]; padded cols
// get mask' = -14427 -> exp2 -> exact 0). One barrier per head via parity double-buffering.
// LDS union: smask (staging, dead after mask-reg extraction) aliases pvred/sao/reds -> 33 KB,
// 4 blocks/CU, whole grid co-resident.
__global__ __launch_bounds__(512, 8) void k_fused(
    const unsigned short* __restrict__ qh, const unsigned short* __restrict__ kh,
    const unsigned short* __restrict__ vt, const unsigned short* __restrict__ ef_bf,
    const unsigned short* __restrict__ wt, const float* __restrict__ bcp,
    const float* __restrict__ mask, float* __restrict__ probs) {
  int wgid = blockIdx.x;                 // 1024
  int xcd = wgid & 7;
  int s = wgid >> 3;
  int nt = s & 15;
  int b = (s >> 4) * 8 + xcd;            // all 16 tiles of b on one XCD
  int tid = threadIdx.x;
  int w = tid >> 6, lane = tid & 63, g = lane >> 4, c = lane & 15;
  int mw = w & 3, nw = w >> 2;
  int nl = nw * 16 + c;                  // attn-phase local n (0..31)
  int nglob = nt * 32 + nl;

  __shared__ __align__(16) char uni[33024];
  unsigned short (*smask)[516] = reinterpret_cast<unsigned short(*)[516]>(uni);          // 33024 B
  float (*pvred)[4][2][16][17] = reinterpret_cast<float(*)[4][2][16][17]>(uni);          // 17408 B
  unsigned short (*sao)[136]   = reinterpret_cast<unsigned short(*)[136]>(uni + 17408);  // 8704 B
  float (*reds)[4][2][16]      = reinterpret_cast<float(*)[4][2][16]>(uni + 17408 + 8704); // 1024 B

  const float LOG2E = 1.4426950408889634f;

  // ---- stage mask' = log2e * mask as bf16 (padded cols -> -14427 => exp2 -> 0) ----
  smask[tid >> 4][500 + (tid & 15)] = f2bf(-14427.0f);
  for (int idx = tid; idx < 32 * 125; idx += 512) {
    int rl = idx / 125;
    int m4 = idx - rl * 125;
    int nr = nt * 32 + rl;
    f32x4 v = {0.f, 0.f, 0.f, 0.f};
    if (nr < NN_) v = *reinterpret_cast<const f32x4*>(mask + ((size_t)b * NN_ + nr) * NN_ + m4 * 4);
    unsigned lo = cvtpk(v[0] * LOG2E, v[1] * LOG2E);
    unsigned hi = cvtpk(v[2] * LOG2E, v[3] * LOG2E);
    *reinterpret_cast<uint2*>(&smask[rl][m4 * 4]) = make_uint2(lo, hi);
  }
  __syncthreads();                        // S1: staging visible

  // this lane's 32 attn-mask' values -> 16 VGPRs (bf16), reused across all 8 heads
  s16x4 mbf[8];
#pragma unroll
  for (int i = 0; i < 8; ++i)
    mbf[i] = *reinterpret_cast<const s16x4*>(&smask[nl][mw * 128 + i * 16 + 4 * g]);
  __syncthreads();                        // S2: smask dead; union region now pvred/sao/reds

  // ================= Phase A: attention, 8 heads, 1 barrier each =================
  for (int h = 0; h < NHEAD; ++h) {
    const unsigned short* qb = qh + ((size_t)(b * NHEAD + h)) * NP * HD;
    const unsigned short* kb = kh + ((size_t)(b * NHEAD + h)) * NP * HD;
    const unsigned short* vrow = vt + (((size_t)(b * NHEAD + h)) * HD + c) * NP;

    s16x4 q4 = *reinterpret_cast<const s16x4*>(qb + nglob * HD + 4 * g);
    s16x8 bq = { q4[0], q4[1], q4[2], q4[3], 0, 0, 0, 0 };

    float lsum = 0.0f;
    f32x4 o = {0, 0, 0, 0};
#pragma unroll
    for (int q8 = 0; q8 < 4; ++q8) {
      int m0 = mw * 128 + q8 * 32;
      s16x4 k4 = *reinterpret_cast<const s16x4*>(kb + (m0 + c) * HD + 4 * g);
      s16x8 kf = { k4[0], k4[1], k4[2], k4[3], 0, 0, 0, 0 };
      f32x4 a0 = MFMA(kf, bq, (f32x4){0,0,0,0});
      k4 = *reinterpret_cast<const s16x4*>(kb + (m0 + 16 + c) * HD + 4 * g);
      s16x8 kf2 = { k4[0], k4[1], k4[2], k4[3], 0, 0, 0, 0 };
      f32x4 a1 = MFMA(kf2, bq, (f32x4){0,0,0,0});
#pragma unroll
      for (int j = 0; j < 4; ++j) {
        a0[j] = EXP2(fmaf(a0[j], 0.36067376022224085f, bf2f((unsigned short)mbf[2 * q8][j])));
        a1[j] = EXP2(fmaf(a1[j], 0.36067376022224085f, bf2f((unsigned short)mbf[2 * q8 + 1][j])));
        lsum += a0[j] + a1[j];
      }
      s16x8 pa = pack8(a0, a1);
      s16x4 va = *reinterpret_cast<const s16x4*>(vrow + m0 + 4 * g);
      s16x4 v2 = *reinterpret_cast<const s16x4*>(vrow + m0 + 16 + 4 * g);
      s16x8 af = { va[0], va[1], va[2], va[3], v2[0], v2[1], v2[2], v2[3] };
      o = MFMA(af, pa, o);
    }
    lsum += __shfl_xor(lsum, 16);
    lsum += __shfl_xor(lsum, 32);
    int par = h & 1;
    if (g == 0) reds[par][mw][nw][c] = lsum;
#pragma unroll
    for (int r = 0; r < 4; ++r) pvred[par][mw][nw][4 * g + r][c] = o[r];
    __syncthreads();                      // one barrier per head
    if (mw == 0) {
      float gsum = reds[par][0][nw][c] + reds[par][1][nw][c] +
                   reds[par][2][nw][c] + reds[par][3][nw][c];
      float inv = RCP(gsum);
      float vv[4];
#pragma unroll
      for (int r = 0; r < 4; ++r) {
        int dd = 4 * g + r;
        vv[r] = (pvred[par][0][nw][dd][c] + pvred[par][1][nw][dd][c] +
                 pvred[par][2][nw][dd][c] + pvred[par][3][nw][dd][c]) * inv;
      }
      *reinterpret_cast<unsigned*>(&sao[nl][h * 16 + 4 * g])     = cvtpk(vv[0], vv[1]);
      *reinterpret_cast<unsigned*>(&sao[nl][h * 16 + 4 * g + 2]) = cvtpk(vv[2], vv[3]);
    }
  }
  __syncthreads();                        // B4: sao (ao tile) complete

  // ================= Phase B: mh = ao @ Wc + bc =================
  float bias0 = bcp[mw * 32 + c];
  float bias1 = bcp[mw * 32 + 16 + c];
  f32x4 acm0 = {0,0,0,0}, acm1 = {0,0,0,0};
#pragma unroll
  for (int kk = 0; kk < 4; ++kk) {
    int k0 = kk * 32 + 8 * g;
    s16x8 aa = *reinterpret_cast<const s16x8*>(&sao[nw * 16 + c][k0]);
    s16x8 bw0 = *reinterpret_cast<const s16x8*>(wt + 4 * 16384 + (mw * 32 + c) * EE + k0);
    s16x8 bw1 = *reinterpret_cast<const s16x8*>(wt + 4 * 16384 + (mw * 32 + 16 + c) * EE + k0);
    acm0 = MFMA(aa, bw0, acm0);
    acm1 = MFMA(aa, bw1, acm1);
  }
  __syncthreads();                        // B5: all sao reads done
#pragma unroll
  for (int r = 0; r < 4; ++r) {
    sao[nw * 16 + 4 * g + r][mw * 32 + c]      = f2bf(acm0[r] + bias0);
    sao[nw * 16 + 4 * g + r][mw * 32 + 16 + c] = f2bf(acm1[r] + bias1);
  }
  __syncthreads();                        // B6: mh tile ready

  // ================= Phase C: pointer logits + softmax (no max-sub; tanh bounds) =====
  s16x8 am[4];
#pragma unroll
  for (int kk = 0; kk < 4; ++kk)
    am[kk] = *reinterpret_cast<const s16x8*>(&sao[nw * 16 + c][kk * 32 + 8 * g]);
  f32x4 sc[8];
#pragma unroll
  for (int t = 0; t < 8; ++t) sc[t] = (f32x4){0,0,0,0};
#pragma unroll
  for (int kk = 0; kk < 4; ++kk) {
    int k0 = kk * 32 + 8 * g;
#pragma unroll
    for (int t = 0; t < 8; ++t) {
      int m = mw * 128 + t * 16 + c;
      s16x8 bfr = *reinterpret_cast<const s16x8*>(ef_bf + ((size_t)(b * NP + m)) * EE + k0);
      sc[t] = MFMA(am[kk], bfr, sc[t]);
    }
  }
  const float* mrow[4];
#pragma unroll
  for (int r = 0; r < 4; ++r) {
    int ng = nt * 32 + nw * 16 + 4 * g + r;
    int ngc = ng < NN_ ? ng : NN_ - 1;
    mrow[r] = mask + ((size_t)b * NN_ + ngc) * NN_;
  }
  float rsum[4] = {0, 0, 0, 0};
#pragma unroll
  for (int t = 0; t < 8; ++t) {
    int m = mw * 128 + t * 16 + c;
    bool mv = (m < NN_);
#pragma unroll
    for (int r = 0; r < 4; ++r) {
      float p = 0.0f;
      if (mv) {
        float x = sc[t][r] * 0.08838834764831845f;   // 1/sqrt(128)
        float ax = fabsf(x);
        float e2 = EXP2(ax * 2.8853900817779268f);   // e^(2|x|)
        float th = copysignf(1.0f - 2.0f * RCP(e2 + 1.0f), x);
        p = EXP2(fmaf(th, 14.426950408889634f, mrow[r][m] * LOG2E));
      }
      sc[t][r] = p;
      rsum[r] += p;
    }
  }
#pragma unroll
  for (int r = 0; r < 4; ++r) {
    rsum[r] += __shfl_xor(rsum[r], 1);
    rsum[r] += __shfl_xor(rsum[r], 2);
    rsum[r] += __shfl_xor(rsum[r], 4);
    rsum[r] += __shfl_xor(rsum[r], 8);
  }
  if (c == 0) {
#pragma unroll
    for (int r = 0; r < 4; ++r) reds[0][mw][nw][4 * g + r] = rsum[r];
  }
  __syncthreads();                        // C2
  float inv[4];
#pragma unroll
  for (int r = 0; r < 4; ++r) {
    int rr = 4 * g + r;
    inv[r] = RCP(reds[0][0][nw][rr] + reds[0][1][nw][rr] +
                 reds[0][2][nw][rr] + reds[0][3][nw][rr]);
  }
#pragma unroll
  for (int t = 0; t < 8; ++t) {
    int m = mw * 128 + t * 16 + c;
    if (m < NN_) {
#pragma unroll
      for (int r = 0; r < 4; ++r) {
        int ng = nt * 32 + nw * 16 + 4 * g + r;
        if (ng < NN_) probs[((size_t)b * NN_ + ng) * NN_ + m] = sc[t][r] * inv[r];
      }
    }
  }
}

extern "C" void kernel_launch(void* const* d_in, const int* in_sizes, int n_in,
                              void* d_out, int out_size, void* d_ws, size_t ws_size,
                              hipStream_t stream) {
  const float* ef   = (const float*)d_in[0];
  const float* eq1  = (const float*)d_in[1];
  const float* eq0  = (const float*)d_in[2];
  const float* mask = (const float*)d_in[3];
  const float* wq1  = (const float*)d_in[4];
  const float* wq0  = (const float*)d_in[5];
  const float* wk   = (const float*)d_in[6];
  const float* wv   = (const float*)d_in[7];
  const float* wc   = (const float*)d_in[8];
  const float* bc   = (const float*)d_in[9];
  float* probs = (float*)d_out;

  char* ws = (char*)d_ws;
  const size_t SL = 8388608;  // 64*512*128*2 bytes
  unsigned short* ef_bf = (unsigned short*)(ws);
  unsigned short* qh    = (unsigned short*)(ws + 1 * SL);
  unsigned short* kh    = (unsigned short*)(ws + 2 * SL);
  unsigned short* vt_bf = (unsigned short*)(ws + 3 * SL);
  unsigned short* wt    = (unsigned short*)(ws + 4 * SL);

  k_conv_ef<<<2048, 256, 0, stream>>>(ef, ef_bf);
  k_conv_w<<<320, 256, 0, stream>>>(wq1, wq0, wk, wv, wc, wt);
  k_proj<<<1024, 256, 0, stream>>>(ef_bf, eq1, eq0, wt, qh, kh, vt_bf);
  k_fused<<<1024, 512, 0, stream>>>(qh, kh, vt_bf, ef_bf, wt, bc, mask, probs);
}

// Round 5
// 204.207 us; speedup vs baseline: 1.0064x; 1.0064x over previous
//
#include <hip/hip_runtime.h>
#include <hip/hip_bf16.h>
#include <cstdint>

#define BB 64
#define NN_ 500
#define NP 512
#define EE 128
#define NHEAD 8
#define HD 16

typedef float f32x4 __attribute__((ext_vector_type(4)));
typedef unsigned u32x4 __attribute__((ext_vector_type(4)));
typedef short s16x8 __attribute__((ext_vector_type(8)));
typedef short s16x4 __attribute__((ext_vector_type(4)));

__device__ __forceinline__ unsigned short f2bf(float f) {
  unsigned u = __builtin_bit_cast(unsigned, f);
  u += 0x7FFFu + ((u >> 16) & 1u);
  return (unsigned short)(u >> 16);
}

__device__ __forceinline__ float bf2f(unsigned short u) {
  unsigned v = ((unsigned)u) << 16;
  return __builtin_bit_cast(float, v);
}

__device__ __forceinline__ unsigned cvtpk(float a, float b) {
  unsigned r;
  asm("v_cvt_pk_bf16_f32 %0, %1, %2" : "=v"(r) : "v"(a), "v"(b));
  return r;
}

__device__ __forceinline__ float EXP2(float x) {
  float r;
  asm("v_exp_f32 %0, %1" : "=v"(r) : "v"(x));
  return r;
}

__device__ __forceinline__ float RCP(float x) {
  float r;
  asm("v_rcp_f32 %0, %1" : "=v"(r) : "v"(x));
  return r;
}

__device__ __forceinline__ s16x8 pack8(f32x4 a, f32x4 b) {
  u32x4 u = { cvtpk(a[0], a[1]), cvtpk(a[2], a[3]), cvtpk(b[0], b[1]), cvtpk(b[2], b[3]) };
  return __builtin_bit_cast(s16x8, u);
}

__device__ __forceinline__ f32x4 MFMA(s16x8 a, s16x8 b, f32x4 c) {
  return __builtin_amdgcn_mfma_f32_16x16x32_bf16(a, b, c, 0, 0, 0);
}

// ---------------- K0a: ef fp32 -> bf16, padded rows 500..511 = 0 ----------------
__global__ void k_conv_ef(const float* __restrict__ ef, unsigned short* __restrict__ out) {
  int idx = blockIdx.x * 256 + threadIdx.x;   // B*NP*16 = 524288
  int e8 = idx & 15;
  int n  = (idx >> 4) & (NP - 1);
  int b  = idx >> 13;
  s16x8 o = {0,0,0,0,0,0,0,0};
  if (n < NN_) {
    const f32x4* p = reinterpret_cast<const f32x4*>(ef + ((size_t)(b * NN_ + n)) * EE + e8 * 8);
    o = pack8(p[0], p[1]);
  }
  *reinterpret_cast<s16x8*>(out + ((size_t)(b * NP + n)) * EE + e8 * 8) = o;
}

// ---------------- K0b: W^T bf16; mats order [q1,q0,k,v,c], WT[m][n][k]=W[k][n] ----------------
__global__ void k_conv_w(const float* __restrict__ w0, const float* __restrict__ w1,
                         const float* __restrict__ w2, const float* __restrict__ w3,
                         const float* __restrict__ w4, unsigned short* __restrict__ wt) {
  int idx = blockIdx.x * 256 + threadIdx.x;   // 5*128*128 = 81920
  int k = idx & 127;
  int n = (idx >> 7) & 127;
  int m = idx >> 14;
  const float* w = (m == 0) ? w0 : (m == 1) ? w1 : (m == 2) ? w2 : (m == 3) ? w3 : w4;
  wt[idx] = f2bf(w[k * 128 + n]);
}

// ---------------- K1: projections -> QH, KH head-major [b][h][n][16], VT [b][h][16][n] ----------------
__global__ __launch_bounds__(256) void k_proj(
    const unsigned short* __restrict__ ef_bf,
    const float* __restrict__ eq1, const float* __restrict__ eq0,
    const unsigned short* __restrict__ wt,
    unsigned short* __restrict__ qh, unsigned short* __restrict__ kh,
    unsigned short* __restrict__ vt_bf) {
  int wgid = blockIdx.x;                 // 1024
  int xcd = wgid & 7;
  int s = wgid >> 3;
  int nt = s & 15;
  int b = (s >> 4) * 8 + xcd;
  int tid = threadIdx.x;
  int w = tid >> 6, lane = tid & 63, g = lane >> 4, c = lane & 15;
  int rw = w & 1, cw = w >> 1;
  int nbase = nt * 32 + rw * 16;

  f32x4 ak[4], av[4], aq[4];
#pragma unroll
  for (int t = 0; t < 4; ++t) { ak[t]=(f32x4){0,0,0,0}; av[t]=(f32x4){0,0,0,0}; aq[t]=(f32x4){0,0,0,0}; }

  int nA = nbase + c;
  int nc = nA < NN_ ? nA : NN_ - 1;

  for (int kk = 0; kk < 4; ++kk) {
    int k0 = kk * 32 + 8 * g;
    s16x8 aef = *reinterpret_cast<const s16x8*>(ef_bf + ((size_t)(b * NP + nA)) * EE + k0);
    const f32x4* p1 = reinterpret_cast<const f32x4*>(eq1 + ((size_t)(b * NN_ + nc)) * EE + k0);
    const f32x4* p0 = reinterpret_cast<const f32x4*>(eq0 + ((size_t)(b * NN_ + nc)) * EE + k0);
    s16x8 a1 = pack8(p1[0], p1[1]);
    s16x8 a0 = pack8(p0[0], p0[1]);
#pragma unroll
    for (int tc = 0; tc < 4; ++tc) {
      int e = cw * 64 + tc * 16 + c;
      const unsigned short* wrow = wt + e * EE + k0;
      s16x8 bq1 = *reinterpret_cast<const s16x8*>(wrow);
      s16x8 bq0 = *reinterpret_cast<const s16x8*>(wrow + 1 * 16384);
      s16x8 bk  = *reinterpret_cast<const s16x8*>(wrow + 2 * 16384);
      s16x8 bv  = *reinterpret_cast<const s16x8*>(wrow + 3 * 16384);
      ak[tc] = MFMA(aef, bk, ak[tc]);
      av[tc] = MFMA(aef, bv, av[tc]);
      aq[tc] = MFMA(a1, bq1, aq[tc]);
      aq[tc] = MFMA(a0, bq0, aq[tc]);
    }
  }
#pragma unroll
  for (int tc = 0; tc < 4; ++tc) {
    int h = cw * 4 + tc;                 // e = cw*64+tc*16+c -> head, d = c
#pragma unroll
    for (int r = 0; r < 4; ++r) {
      int n = nbase + 4 * g + r;
      size_t off = ((size_t)((b * NHEAD + h) * NP) + n) * HD + c;
      kh[off] = f2bf(ak[tc][r]);         // padded rows: ef=0 -> ak=0, naturally safe
      qh[off] = f2bf(aq[tc][r]);         // padded rows garbage-but-finite; outputs unused
    }
    int n0 = nbase + 4 * g;
    unsigned pv0 = cvtpk(av[tc][0], av[tc][1]);
    unsigned pv1 = cvtpk(av[tc][2], av[tc][3]);
    *reinterpret_cast<uint2*>(vt_bf + (((size_t)(b * NHEAD + h)) * HD + c) * NP + n0) =
        make_uint2(pv0, pv1);
  }
}

// ---------------- K2: FUSED attn(8 heads) + combine + pointer-logits per (b, 32-row tile) ----------------
// 512 threads = 8 waves: mw = w&3 (m-split 4-way), nw = w>>2 (n-split 2-way).
// No max-subtraction (attn scores small; pointer logits bounded by 10*tanh; padded cols get
// mask' = -14427 -> exp2 -> exact 0). Mask stays in LDS (bf16, pre-scaled by log2e) for BOTH
// softmaxes. LDS total 50944 B -> 3 blocks/CU; launch_bounds(512,6) -> VGPR cap 85, no spill.
__global__ __launch_bounds__(512, 6) void k_fused(
    const unsigned short* __restrict__ qh, const unsigned short* __restrict__ kh,
    const unsigned short* __restrict__ vt, const unsigned short* __restrict__ ef_bf,
    const unsigned short* __restrict__ wt, const float* __restrict__ bcp,
    const float* __restrict__ mask, float* __restrict__ probs) {
  int wgid = blockIdx.x;                 // 1024
  int xcd = wgid & 7;
  int s = wgid >> 3;
  int nt = s & 15;
  int b = (s >> 4) * 8 + xcd;            // all 16 tiles of b on one XCD
  int tid = threadIdx.x;
  int w = tid >> 6, lane = tid & 63, g = lane >> 4, c = lane & 15;
  int mw = w & 3, nw = w >> 2;
  int nl = nw * 16 + c;                  // attn-phase local n (0..31)
  int nglob = nt * 32 + nl;

  __shared__ unsigned short smask[32][516];   // 33024 B, bf16 mask' = log2e*mask, lives whole kernel
  __shared__ float pvred[4][2][16][17];       // 8704 B
  __shared__ unsigned short sao[32][136];     // 8704 B, ao tile then mh tile (aliased by phase)
  __shared__ float reds[4][2][16];            // 512 B   -> 50944 B total

  const float LOG2E = 1.4426950408889634f;

  // ---- stage mask' = log2e * mask as bf16 (padded cols -> -14427 => exp2 -> 0) ----
  smask[tid >> 4][500 + (tid & 15)] = f2bf(-14427.0f);
  for (int idx = tid; idx < 32 * 125; idx += 512) {
    int rl = idx / 125;
    int m4 = idx - rl * 125;
    int nr = nt * 32 + rl;
    f32x4 v = {0.f, 0.f, 0.f, 0.f};
    if (nr < NN_) v = *reinterpret_cast<const f32x4*>(mask + ((size_t)b * NN_ + nr) * NN_ + m4 * 4);
    unsigned lo = cvtpk(v[0] * LOG2E, v[1] * LOG2E);
    unsigned hi = cvtpk(v[2] * LOG2E, v[3] * LOG2E);
    *reinterpret_cast<uint2*>(&smask[rl][m4 * 4]) = make_uint2(lo, hi);
  }
  __syncthreads();                        // S1: smask visible

  // this lane's 32 attn-mask' values -> 8 VGPRs (bf16), reused across all 8 heads
  s16x4 mbf[8];
#pragma unroll
  for (int i = 0; i < 8; ++i)
    mbf[i] = *reinterpret_cast<const s16x4*>(&smask[nl][mw * 128 + i * 16 + 4 * g]);

  // ================= Phase A: attention, 8 heads, 2 barriers each =================
  for (int h = 0; h < NHEAD; ++h) {
    const unsigned short* qb = qh + ((size_t)(b * NHEAD + h)) * NP * HD;
    const unsigned short* kb = kh + ((size_t)(b * NHEAD + h)) * NP * HD;
    const unsigned short* vrow = vt + (((size_t)(b * NHEAD + h)) * HD + c) * NP;

    s16x4 q4 = *reinterpret_cast<const s16x4*>(qb + nglob * HD + 4 * g);
    s16x8 bq = { q4[0], q4[1], q4[2], q4[3], 0, 0, 0, 0 };

    float lsum = 0.0f;
    f32x4 o = {0, 0, 0, 0};
#pragma unroll
    for (int q8 = 0; q8 < 4; ++q8) {
      int m0 = mw * 128 + q8 * 32;
      s16x4 k4 = *reinterpret_cast<const s16x4*>(kb + (m0 + c) * HD + 4 * g);
      s16x8 kf = { k4[0], k4[1], k4[2], k4[3], 0, 0, 0, 0 };
      f32x4 a0 = MFMA(kf, bq, (f32x4){0,0,0,0});
      k4 = *reinterpret_cast<const s16x4*>(kb + (m0 + 16 + c) * HD + 4 * g);
      s16x8 kf2 = { k4[0], k4[1], k4[2], k4[3], 0, 0, 0, 0 };
      f32x4 a1 = MFMA(kf2, bq, (f32x4){0,0,0,0});
#pragma unroll
      for (int j = 0; j < 4; ++j) {
        a0[j] = EXP2(fmaf(a0[j], 0.36067376022224085f, bf2f((unsigned short)mbf[2 * q8][j])));
        a1[j] = EXP2(fmaf(a1[j], 0.36067376022224085f, bf2f((unsigned short)mbf[2 * q8 + 1][j])));
        lsum += a0[j] + a1[j];
      }
      s16x8 pa = pack8(a0, a1);
      s16x4 va = *reinterpret_cast<const s16x4*>(vrow + m0 + 4 * g);
      s16x4 v2 = *reinterpret_cast<const s16x4*>(vrow + m0 + 16 + 4 * g);
      s16x8 af = { va[0], va[1], va[2], va[3], v2[0], v2[1], v2[2], v2[3] };
      o = MFMA(af, pa, o);
    }
    lsum += __shfl_xor(lsum, 16);
    lsum += __shfl_xor(lsum, 32);
    if (g == 0) reds[mw][nw][c] = lsum;
#pragma unroll
    for (int r = 0; r < 4; ++r) pvred[mw][nw][4 * g + r][c] = o[r];
    __syncthreads();                      // A1: partials visible
    if (mw == 0) {
      float gsum = reds[0][nw][c] + reds[1][nw][c] + reds[2][nw][c] + reds[3][nw][c];
      float inv = RCP(gsum);
      float vv[4];
#pragma unroll
      for (int r = 0; r < 4; ++r) {
        int dd = 4 * g + r;
        vv[r] = (pvred[0][nw][dd][c] + pvred[1][nw][dd][c] +
                 pvred[2][nw][dd][c] + pvred[3][nw][dd][c]) * inv;
      }
      *reinterpret_cast<unsigned*>(&sao[nl][h * 16 + 4 * g])     = cvtpk(vv[0], vv[1]);
      *reinterpret_cast<unsigned*>(&sao[nl][h * 16 + 4 * g + 2]) = cvtpk(vv[2], vv[3]);
    }
    __syncthreads();                      // A2: pvred reads done before next head overwrites
  }

  // ================= Phase B: mh = ao @ Wc + bc =================
  float bias0 = bcp[mw * 32 + c];
  float bias1 = bcp[mw * 32 + 16 + c];
  f32x4 acm0 = {0,0,0,0}, acm1 = {0,0,0,0};
#pragma unroll
  for (int kk = 0; kk < 4; ++kk) {
    int k0 = kk * 32 + 8 * g;
    s16x8 aa = *reinterpret_cast<const s16x8*>(&sao[nw * 16 + c][k0]);
    s16x8 bw0 = *reinterpret_cast<const s16x8*>(wt + 4 * 16384 + (mw * 32 + c) * EE + k0);
    s16x8 bw1 = *reinterpret_cast<const s16x8*>(wt + 4 * 16384 + (mw * 32 + 16 + c) * EE + k0);
    acm0 = MFMA(aa, bw0, acm0);
    acm1 = MFMA(aa, bw1, acm1);
  }
  __syncthreads();                        // B1: all sao reads done
#pragma unroll
  for (int r = 0; r < 4; ++r) {
    sao[nw * 16 + 4 * g + r][mw * 32 + c]      = f2bf(acm0[r] + bias0);
    sao[nw * 16 + 4 * g + r][mw * 32 + 16 + c] = f2bf(acm1[r] + bias1);
  }
  __syncthreads();                        // B2: mh tile ready

  // ================= Phase C: pointer logits + softmax (no max-sub; tanh bounds) =====
  f32x4 sc[8];
#pragma unroll
  for (int t = 0; t < 8; ++t) sc[t] = (f32x4){0,0,0,0};
#pragma unroll
  for (int kk = 0; kk < 4; ++kk) {
    int k0 = kk * 32 + 8 * g;
    s16x8 am = *reinterpret_cast<const s16x8*>(&sao[nw * 16 + c][k0]);
#pragma unroll
    for (int t = 0; t < 8; ++t) {
      int m = mw * 128 + t * 16 + c;
      s16x8 bfr = *reinterpret_cast<const s16x8*>(ef_bf + ((size_t)(b * NP + m)) * EE + k0);
      sc[t] = MFMA(am, bfr, sc[t]);
    }
  }
  float rsum[4] = {0, 0, 0, 0};
#pragma unroll
  for (int t = 0; t < 8; ++t) {
    int m = mw * 128 + t * 16 + c;
#pragma unroll
    for (int r = 0; r < 4; ++r) {
      float x = sc[t][r] * 0.08838834764831845f;   // 1/sqrt(128)
      float ax = fabsf(x);
      float e2 = EXP2(ax * 2.8853900817779268f);   // e^(2|x|)
      float th = copysignf(1.0f - 2.0f * RCP(e2 + 1.0f), x);
      float p = EXP2(fmaf(th, 14.426950408889634f, bf2f(smask[nw * 16 + 4 * g + r][m])));
      sc[t][r] = p;                                 // m>=500 -> mask'=-14427 -> p=0
      rsum[r] += p;
    }
  }
#pragma unroll
  for (int r = 0; r < 4; ++r) {
    rsum[r] += __shfl_xor(rsum[r], 1);
    rsum[r] += __shfl_xor(rsum[r], 2);
    rsum[r] += __shfl_xor(rsum[r], 4);
    rsum[r] += __shfl_xor(rsum[r], 8);
  }
  if (c == 0) {
#pragma unroll
    for (int r = 0; r < 4; ++r) reds[mw][nw][4 * g + r] = rsum[r];
  }
  __syncthreads();                        // C1
  float inv[4];
#pragma unroll
  for (int r = 0; r < 4; ++r) {
    int rr = 4 * g + r;
    inv[r] = RCP(reds[0][nw][rr] + reds[1][nw][rr] + reds[2][nw][rr] + reds[3][nw][rr]);
  }
#pragma unroll
  for (int t = 0; t < 8; ++t) {
    int m = mw * 128 + t * 16 + c;
    if (m < NN_) {
#pragma unroll
      for (int r = 0; r < 4; ++r) {
        int ng = nt * 32 + nw * 16 + 4 * g + r;
        if (ng < NN_) probs[((size_t)b * NN_ + ng) * NN_ + m] = sc[t][r] * inv[r];
      }
    }
  }
}

extern "C" void kernel_launch(void* const* d_in, const int* in_sizes, int n_in,
                              void* d_out, int out_size, void* d_ws, size_t ws_size,
                              hipStream_t stream) {
  const float* ef   = (const float*)d_in[0];
  const float* eq1  = (const float*)d_in[1];
  const float* eq0  = (const float*)d_in[2];
  const float* mask = (const float*)d_in[3];
  const float* wq1  = (const float*)d_in[4];
  const float* wq0  = (const float*)d_in[5];
  const float* wk   = (const float*)d_in[6];
  const float* wv   = (const float*)d_in[7];
  const float* wc   = (const float*)d_in[8];
  const float* bc   = (const float*)d_in[9];
  float* probs = (float*)d_out;

  char* ws = (char*)d_ws;
  const size_t SL = 8388608;  // 64*512*128*2 bytes
  unsigned short* ef_bf = (unsigned short*)(ws);
  unsigned short* qh    = (unsigned short*)(ws + 1 * SL);
  unsigned short* kh    = (unsigned short*)(ws + 2 * SL);
  unsigned short* vt_bf = (unsigned short*)(ws + 3 * SL);
  unsigned short* wt    = (unsigned short*)(ws + 4 * SL);

  k_conv_ef<<<2048, 256, 0, stream>>>(ef, ef_bf);
  k_conv_w<<<320, 256, 0, stream>>>(wq1, wq0, wk, wv, wc, wt);
  k_proj<<<1024, 256, 0, stream>>>(ef_bf, eq1, eq0, wt, qh, kh, vt_bf);
  k_fused<<<1024, 512, 0, stream>>>(qh, kh, vt_bf, ef_bf, wt, bc, mask, probs);
}

// Round 7
// 177.983 us; speedup vs baseline: 1.1546x; 1.1473x over previous
//
#include <hip/hip_runtime.h>
#include <hip/hip_bf16.h>
#include <cstdint>

#define BB 64
#define NN_ 500
#define NP 512
#define EE 128
#define NHEAD 8
#define HD 16

typedef float f32x4 __attribute__((ext_vector_type(4)));
typedef unsigned u32x4 __attribute__((ext_vector_type(4)));
typedef short s16x8 __attribute__((ext_vector_type(8)));
typedef short s16x4 __attribute__((ext_vector_type(4)));

__device__ __forceinline__ unsigned short f2bf(float f) {
  unsigned u = __builtin_bit_cast(unsigned, f);
  u += 0x7FFFu + ((u >> 16) & 1u);
  return (unsigned short)(u >> 16);
}

__device__ __forceinline__ float bf2f(unsigned short u) {
  unsigned v = ((unsigned)u) << 16;
  return __builtin_bit_cast(float, v);
}

__device__ __forceinline__ unsigned cvtpk(float a, float b) {
  unsigned r;
  asm("v_cvt_pk_bf16_f32 %0, %1, %2" : "=v"(r) : "v"(a), "v"(b));
  return r;
}

// cvtpk whose result feeds an MFMA operand: pad 2 wait-states inside the asm so the
// VALU-write -> MFMA-read distance is guaranteed independent of scheduling.
__device__ __forceinline__ unsigned cvtpk_m(float a, float b) {
  unsigned r;
  asm("v_cvt_pk_bf16_f32 %0, %1, %2\n\ts_nop 1" : "=v"(r) : "v"(a), "v"(b));
  return r;
}

__device__ __forceinline__ float EXP2(float x) {
  float r;
  asm("v_exp_f32 %0, %1" : "=v"(r) : "v"(x));
  return r;
}

__device__ __forceinline__ float RCP(float x) {
  float r;
  asm("v_rcp_f32 %0, %1" : "=v"(r) : "v"(x));
  return r;
}

__device__ __forceinline__ s16x8 pack8(f32x4 a, f32x4 b) {
  u32x4 u = { cvtpk(a[0], a[1]), cvtpk(a[2], a[3]), cvtpk(b[0], b[1]), cvtpk(b[2], b[3]) };
  return __builtin_bit_cast(s16x8, u);
}

__device__ __forceinline__ s16x8 pack8_m(f32x4 a, f32x4 b) {
  u32x4 u = { cvtpk_m(a[0], a[1]), cvtpk_m(a[2], a[3]), cvtpk_m(b[0], b[1]), cvtpk_m(b[2], b[3]) };
  return __builtin_bit_cast(s16x8, u);
}

__device__ __forceinline__ f32x4 MFMA(s16x8 a, s16x8 b, f32x4 c) {
  return __builtin_amdgcn_mfma_f32_16x16x32_bf16(a, b, c, 0, 0, 0);
}

// ---------------- K0a: ef fp32 -> bf16, padded rows 500..511 = 0 ----------------
__global__ void k_conv_ef(const float* __restrict__ ef, unsigned short* __restrict__ out) {
  int idx = blockIdx.x * 256 + threadIdx.x;   // B*NP*16 = 524288
  int e8 = idx & 15;
  int n  = (idx >> 4) & (NP - 1);
  int b  = idx >> 13;
  s16x8 o = {0,0,0,0,0,0,0,0};
  if (n < NN_) {
    const f32x4* p = reinterpret_cast<const f32x4*>(ef + ((size_t)(b * NN_ + n)) * EE + e8 * 8);
    o = pack8(p[0], p[1]);
  }
  *reinterpret_cast<s16x8*>(out + ((size_t)(b * NP + n)) * EE + e8 * 8) = o;
}

// ---------------- K0b: W^T bf16; mats order [q1,q0,k,v,c], WT[m][n][k]=W[k][n] ----------------
__global__ void k_conv_w(const float* __restrict__ w0, const float* __restrict__ w1,
                         const float* __restrict__ w2, const float* __restrict__ w3,
                         const float* __restrict__ w4, unsigned short* __restrict__ wt) {
  int idx = blockIdx.x * 256 + threadIdx.x;   // 5*128*128 = 81920
  int k = idx & 127;
  int n = (idx >> 7) & 127;
  int m = idx >> 14;
  const float* w = (m == 0) ? w0 : (m == 1) ? w1 : (m == 2) ? w2 : (m == 3) ? w3 : w4;
  wt[idx] = f2bf(w[k * 128 + n]);
}

// ---------------- K1: projections -> QH, KH head-major [b][h][n][16], VT [b][h][16][n] ----------------
__global__ __launch_bounds__(256) void k_proj(
    const unsigned short* __restrict__ ef_bf,
    const float* __restrict__ eq1, const float* __restrict__ eq0,
    const unsigned short* __restrict__ wt,
    unsigned short* __restrict__ qh, unsigned short* __restrict__ kh,
    unsigned short* __restrict__ vt_bf) {
  int wgid = blockIdx.x;                 // 1024
  int xcd = wgid & 7;
  int s = wgid >> 3;
  int nt = s & 15;
  int b = (s >> 4) * 8 + xcd;
  int tid = threadIdx.x;
  int w = tid >> 6, lane = tid & 63, g = lane >> 4, c = lane & 15;
  int rw = w & 1, cw = w >> 1;
  int nbase = nt * 32 + rw * 16;

  f32x4 ak[4], av[4], aq[4];
#pragma unroll
  for (int t = 0; t < 4; ++t) { ak[t]=(f32x4){0,0,0,0}; av[t]=(f32x4){0,0,0,0}; aq[t]=(f32x4){0,0,0,0}; }

  int nA = nbase + c;
  int nc = nA < NN_ ? nA : NN_ - 1;

  for (int kk = 0; kk < 4; ++kk) {
    int k0 = kk * 32 + 8 * g;
    s16x8 aef = *reinterpret_cast<const s16x8*>(ef_bf + ((size_t)(b * NP + nA)) * EE + k0);
    const f32x4* p1 = reinterpret_cast<const f32x4*>(eq1 + ((size_t)(b * NN_ + nc)) * EE + k0);
    const f32x4* p0 = reinterpret_cast<const f32x4*>(eq0 + ((size_t)(b * NN_ + nc)) * EE + k0);
    s16x8 a1 = pack8(p1[0], p1[1]);
    s16x8 a0 = pack8(p0[0], p0[1]);
#pragma unroll
    for (int tc = 0; tc < 4; ++tc) {
      int e = cw * 64 + tc * 16 + c;
      const unsigned short* wrow = wt + e * EE + k0;
      s16x8 bq1 = *reinterpret_cast<const s16x8*>(wrow);
      s16x8 bq0 = *reinterpret_cast<const s16x8*>(wrow + 1 * 16384);
      s16x8 bk  = *reinterpret_cast<const s16x8*>(wrow + 2 * 16384);
      s16x8 bv  = *reinterpret_cast<const s16x8*>(wrow + 3 * 16384);
      ak[tc] = MFMA(aef, bk, ak[tc]);
      av[tc] = MFMA(aef, bv, av[tc]);
      aq[tc] = MFMA(a1, bq1, aq[tc]);
      aq[tc] = MFMA(a0, bq0, aq[tc]);
    }
  }
#pragma unroll
  for (int tc = 0; tc < 4; ++tc) {
    int h = cw * 4 + tc;                 // e = cw*64+tc*16+c -> head, d = c
#pragma unroll
    for (int r = 0; r < 4; ++r) {
      int n = nbase + 4 * g + r;
      size_t off = ((size_t)((b * NHEAD + h) * NP) + n) * HD + c;
      kh[off] = f2bf(ak[tc][r]);         // padded rows: ef=0 -> ak=0, naturally safe
      qh[off] = f2bf(aq[tc][r]);         // padded rows garbage-but-finite; outputs unused
    }
    int n0 = nbase + 4 * g;
    unsigned pv0 = cvtpk(av[tc][0], av[tc][1]);
    unsigned pv1 = cvtpk(av[tc][2], av[tc][3]);
    *reinterpret_cast<uint2*>(vt_bf + (((size_t)(b * NHEAD + h)) * HD + c) * NP + n0) =
        make_uint2(pv0, pv1);
  }
}

// ---------------- K2: FUSED attn + combine + pointer-logits per (b, 32-row tile) ----------------
// 512 threads = 8 waves. Phase A: wave w owns head h=w completely; the 32 q-rows are done as
// two sequential 16-row halves (fewer live regs). Swapped QK^T (S^T = mfma(K,Q)) makes the
// softmax-over-m lane-local (+shfl over g); PV accumulates in registers across the whole
// m-loop. Zero barriers inside Phase A. No max-subtraction anywhere (attn scores bounded,
// pointer logits bounded by 10*tanh; padded cols carry mask' = -14427 -> exp2 -> exact 0).
__global__ __launch_bounds__(512, 4) void k_fused(
    const unsigned short* __restrict__ qh, const unsigned short* __restrict__ kh,
    const unsigned short* __restrict__ vt, const unsigned short* __restrict__ ef_bf,
    const unsigned short* __restrict__ wt, const float* __restrict__ bcp,
    const float* __restrict__ mask, float* __restrict__ probs) {
  int wgid = blockIdx.x;                 // 1024
  int xcd = wgid & 7;
  int s = wgid >> 3;
  int nt = s & 15;
  int b = (s >> 4) * 8 + xcd;            // all 16 tiles of b on one XCD
  int tid = threadIdx.x;
  int w = tid >> 6, lane = tid & 63, g = lane >> 4, c = lane & 15;
  int nt32 = nt * 32;

  __shared__ unsigned short smask[32][516];   // 33024 B, bf16 mask' = log2e*mask
  __shared__ unsigned short sao[32][136];     // 8704 B, ao tile then mh tile (aliased by phase)
  __shared__ float reds[4][2][16];            // 512 B -> 42240 B total

  const float LOG2E = 1.4426950408889634f;

  // ---- stage mask' = log2e * mask as bf16 (padded cols -> -14427 => exp2 -> 0) ----
  smask[tid >> 4][500 + (tid & 15)] = f2bf(-14427.0f);
  for (int idx = tid; idx < 32 * 125; idx += 512) {
    int rl = idx / 125;
    int m4 = idx - rl * 125;
    int nr = nt32 + rl;
    f32x4 v = {0.f, 0.f, 0.f, 0.f};
    if (nr < NN_) v = *reinterpret_cast<const f32x4*>(mask + ((size_t)b * NN_ + nr) * NN_ + m4 * 4);
    unsigned lo = cvtpk(v[0] * LOG2E, v[1] * LOG2E);
    unsigned hi = cvtpk(v[2] * LOG2E, v[3] * LOG2E);
    *reinterpret_cast<uint2*>(&smask[rl][m4 * 4]) = make_uint2(lo, hi);
  }
  __syncthreads();                        // S1: smask visible

  // ================= Phase A: attention, wave w = head w, zero barriers =================
  {
    int h = w;
    const unsigned short* qb = qh + ((size_t)(b * NHEAD + h)) * NP * HD;
    const unsigned short* kb = kh + ((size_t)(b * NHEAD + h)) * NP * HD;
    const unsigned short* vrow = vt + (((size_t)(b * NHEAD + h)) * HD + c) * NP;

    for (int hf = 0; hf < 2; ++hf) {
      int ro = hf * 16;                  // n-row offset within tile
      s16x4 q4 = *reinterpret_cast<const s16x4*>(qb + (nt32 + ro + c) * HD + 4 * g);
      s16x8 bq = { q4[0], q4[1], q4[2], q4[3], 0, 0, 0, 0 };

      f32x4 o = {0, 0, 0, 0};
      float ls = 0.0f;
      for (int mt = 0; mt < 16; ++mt) {
        int m0 = mt * 32;
        s16x4 k40 = *reinterpret_cast<const s16x4*>(kb + (m0 + c) * HD + 4 * g);
        s16x4 k41 = *reinterpret_cast<const s16x4*>(kb + (m0 + 16 + c) * HD + 4 * g);
        s16x8 kf0 = { k40[0], k40[1], k40[2], k40[3], 0, 0, 0, 0 };
        s16x8 kf1 = { k41[0], k41[1], k41[2], k41[3], 0, 0, 0, 0 };
        s16x4 mk0 = *reinterpret_cast<const s16x4*>(&smask[ro + c][m0 + 4 * g]);
        s16x4 mk1 = *reinterpret_cast<const s16x4*>(&smask[ro + c][m0 + 16 + 4 * g]);
        f32x4 a0 = MFMA(kf0, bq, (f32x4){0,0,0,0});
        f32x4 a1 = MFMA(kf1, bq, (f32x4){0,0,0,0});
#pragma unroll
        for (int j = 0; j < 4; ++j) {
          a0[j] = EXP2(fmaf(a0[j], 0.36067376022224085f, bf2f((unsigned short)mk0[j])));
          a1[j] = EXP2(fmaf(a1[j], 0.36067376022224085f, bf2f((unsigned short)mk1[j])));
          ls += a0[j] + a1[j];
        }
        s16x8 pa = pack8_m(a0, a1);      // s_nop-hardened: feeds MFMA SrcB
        s16x4 va = *reinterpret_cast<const s16x4*>(vrow + m0 + 4 * g);
        s16x4 v2 = *reinterpret_cast<const s16x4*>(vrow + m0 + 16 + 4 * g);
        s16x8 af = { va[0], va[1], va[2], va[3], v2[0], v2[1], v2[2], v2[3] };
        o = MFMA(af, pa, o);
      }
      ls += __shfl_xor(ls, 16);
      ls += __shfl_xor(ls, 32);
      float inv = RCP(ls);
      *reinterpret_cast<uint2*>(&sao[ro + c][h * HD + 4 * g]) =
          make_uint2(cvtpk(o[0] * inv, o[1] * inv), cvtpk(o[2] * inv, o[3] * inv));
    }
  }
  __syncthreads();                        // A1: sao (ao tile) complete

  // ================= Phase B: mh = ao @ Wc + bc =================
  int mw = w & 3, nw = w >> 2;
  float bias0 = bcp[mw * 32 + c];
  float bias1 = bcp[mw * 32 + 16 + c];
  f32x4 acm0 = {0,0,0,0}, acm1 = {0,0,0,0};
#pragma unroll
  for (int kk = 0; kk < 4; ++kk) {
    int k0 = kk * 32 + 8 * g;
    s16x8 aa = *reinterpret_cast<const s16x8*>(&sao[nw * 16 + c][k0]);
    s16x8 bw0 = *reinterpret_cast<const s16x8*>(wt + 4 * 16384 + (mw * 32 + c) * EE + k0);
    s16x8 bw1 = *reinterpret_cast<const s16x8*>(wt + 4 * 16384 + (mw * 32 + 16 + c) * EE + k0);
    acm0 = MFMA(aa, bw0, acm0);
    acm1 = MFMA(aa, bw1, acm1);
  }
  __syncthreads();                        // B1: all sao reads done
#pragma unroll
  for (int r = 0; r < 4; ++r) {
    sao[nw * 16 + 4 * g + r][mw * 32 + c]      = f2bf(acm0[r] + bias0);
    sao[nw * 16 + 4 * g + r][mw * 32 + 16 + c] = f2bf(acm1[r] + bias1);
  }
  __syncthreads();                        // B2: mh tile ready

  // ================= Phase C: pointer logits + softmax (no max-sub; tanh bounds) =====
  f32x4 sc[8];
#pragma unroll
  for (int t = 0; t < 8; ++t) sc[t] = (f32x4){0,0,0,0};
#pragma unroll
  for (int kk = 0; kk < 4; ++kk) {
    int k0 = kk * 32 + 8 * g;
    s16x8 am = *reinterpret_cast<const s16x8*>(&sao[nw * 16 + c][k0]);
#pragma unroll
    for (int t = 0; t < 8; ++t) {
      int m = mw * 128 + t * 16 + c;
      s16x8 bfr = *reinterpret_cast<const s16x8*>(ef_bf + ((size_t)(b * NP + m)) * EE + k0);
      sc[t] = MFMA(am, bfr, sc[t]);
    }
  }
  float rsum[4] = {0, 0, 0, 0};
#pragma unroll
  for (int t = 0; t < 8; ++t) {
    int m = mw * 128 + t * 16 + c;
#pragma unroll
    for (int r = 0; r < 4; ++r) {
      float x = sc[t][r] * 0.08838834764831845f;   // 1/sqrt(128)
      float ax = fabsf(x);
      float e2 = EXP2(ax * 2.8853900817779268f);   // e^(2|x|)
      float th = copysignf(1.0f - 2.0f * RCP(e2 + 1.0f), x);
      float p = EXP2(fmaf(th, 14.426950408889634f, bf2f(smask[nw * 16 + 4 * g + r][m])));
      sc[t][r] = p;                                 // m>=500 -> mask'=-14427 -> p=0
      rsum[r] += p;
    }
  }
#pragma unroll
  for (int r = 0; r < 4; ++r) {
    rsum[r] += __shfl_xor(rsum[r], 1);
    rsum[r] += __shfl_xor(rsum[r], 2);
    rsum[r] += __shfl_xor(rsum[r], 4);
    rsum[r] += __shfl_xor(rsum[r], 8);
  }
  if (c == 0) {
#pragma unroll
    for (int r = 0; r < 4; ++r) reds[mw][nw][4 * g + r] = rsum[r];
  }
  __syncthreads();                        // C1
  float inv[4];
#pragma unroll
  for (int r = 0; r < 4; ++r) {
    int rr = 4 * g + r;
    inv[r] = RCP(reds[0][nw][rr] + reds[1][nw][rr] + reds[2][nw][rr] + reds[3][nw][rr]);
  }
#pragma unroll
  for (int t = 0; t < 8; ++t) {
    int m = mw * 128 + t * 16 + c;
    if (m < NN_) {
#pragma unroll
      for (int r = 0; r < 4; ++r) {
        int ng = nt32 + nw * 16 + 4 * g + r;
        if (ng < NN_) probs[((size_t)b * NN_ + ng) * NN_ + m] = sc[t][r] * inv[r];
      }
    }
  }
}

extern "C" void kernel_launch(void* const* d_in, const int* in_sizes, int n_in,
                              void* d_out, int out_size, void* d_ws, size_t ws_size,
                              hipStream_t stream) {
  const float* ef   = (const float*)d_in[0];
  const float* eq1  = (const float*)d_in[1];
  const float* eq0  = (const float*)d_in[2];
  const float* mask = (const float*)d_in[3];
  const float* wq1  = (const float*)d_in[4];
  const float* wq0  = (const float*)d_in[5];
  const float* wk   = (const float*)d_in[6];
  const float* wv   = (const float*)d_in[7];
  const float* wc   = (const float*)d_in[8];
  const float* bc   = (const float*)d_in[9];
  float* probs = (float*)d_out;

  char* ws = (char*)d_ws;
  const size_t SL = 8388608;  // 64*512*128*2 bytes
  unsigned short* ef_bf = (unsigned short*)(ws);
  unsigned short* qh    = (unsigned short*)(ws + 1 * SL);
  unsigned short* kh    = (unsigned short*)(ws + 2 * SL);
  unsigned short* vt_bf = (unsigned short*)(ws + 3 * SL);
  unsigned short* wt    = (unsigned short*)(ws + 4 * SL);

  k_conv_ef<<<2048, 256, 0, stream>>>(ef, ef_bf);
  k_conv_w<<<320, 256, 0, stream>>>(wq1, wq0, wk, wv, wc, wt);
  k_proj<<<1024, 256, 0, stream>>>(ef_bf, eq1, eq0, wt, qh, kh, vt_bf);
  k_fused<<<1024, 512, 0, stream>>>(qh, kh, vt_bf, ef_bf, wt, bc, mask, probs);
}